// Round 7
// baseline (34.855 us; speedup 1.0000x reference)
//
#include <hip/hip_runtime.h>

// ---------------------------------------------------------------------------
// Precompute kernel: builds the four 81-element coefficient tensors C[mi][q]
// such that  z_q = sum_{mi} C[mi][q] * prod_q w_q[m_q],
// where w_q = (1+cos x_q, sin x_q, 1-cos x_q)   (1/16 folded into C).
//
// psi = D r (r real tensor-product), final = V psi = U r with U = V*D.
// z_q = sum over ordered pairs (j,k) of r_j r_k * M^q_jk,
// M^q_jk = sum_i sign_q(i) Re(conj(U_ij) U_ik).
// Pairs grouped by per-qubit signature m_q = j_q + k_q in {0,1,2}.
// ---------------------------------------------------------------------------
__global__ __launch_bounds__(256) void qprecomp(const float* __restrict__ params,
                                                float* __restrict__ C) {
  __shared__ float colR[16][16];   // colR[j][i] = Re U_ij
  __shared__ float colI[16][16];
  __shared__ float Um[12][8];      // per-gate 2x2 complex (m00,m01,m10,m11)
  __shared__ float4 S4[256];       // per ordered pair (j,k): the 4 signed sums
  const int t = threadIdx.x;

  if (t < 16) {
#pragma unroll
    for (int i = 0; i < 16; ++i) { colR[t][i] = 0.0f; colI[t][i] = 0.0f; }
    int pc = __popc(t) & 3;
    colR[t][t] = (pc == 0) ? 1.0f : (pc == 2 ? -1.0f : 0.0f);
    colI[t][t] = (pc == 1) ? -1.0f : (pc == 3 ? 1.0f : 0.0f);
  }
  if (t < 12) {
    float phi = params[t * 3 + 0], th = params[t * 3 + 1], om = params[t * 3 + 2];
    float sa = __sinf(0.5f * (phi + om)), ca = __cosf(0.5f * (phi + om));
    float sb = __sinf(0.5f * (phi - om)), cb = __cosf(0.5f * (phi - om));
    float s2 = __sinf(0.5f * th),         c2 = __cosf(0.5f * th);
    Um[t][0] =  c2 * ca; Um[t][1] = -c2 * sa;   // m00 = e^{-i a} c
    Um[t][2] = -s2 * cb; Um[t][3] = -s2 * sb;   // m01 = -e^{+i b} s
    Um[t][4] =  s2 * cb; Um[t][5] = -s2 * sb;   // m10 =  e^{-i b} s
    Um[t][6] =  c2 * ca; Um[t][7] =  c2 * sa;   // m11 = e^{+i a} c
  }
  __syncthreads();

  const int j = t >> 3, p = t & 7;  // column j, pair p (valid for t<128)
  for (int l = 0; l < 3; ++l) {
    for (int q = 0; q < 4; ++q) {
      if (t < 128) {
        const int g = l * 4 + q;
        const int B = 3 - q, mask = 1 << B;                 // qubit q = bit (3-q)
        const int i0 = ((p >> B) << (B + 1)) | (p & (mask - 1));
        const int i1 = i0 | mask;
        float a0r = colR[j][i0], a0i = colI[j][i0];
        float a1r = colR[j][i1], a1i = colI[j][i1];
        float m00r = Um[g][0], m00i = Um[g][1], m01r = Um[g][2], m01i = Um[g][3];
        float m10r = Um[g][4], m10i = Um[g][5], m11r = Um[g][6], m11i = Um[g][7];
        colR[j][i0] = m00r * a0r - m00i * a0i + m01r * a1r - m01i * a1i;
        colI[j][i0] = m00r * a0i + m00i * a0r + m01r * a1i + m01i * a1r;
        colR[j][i1] = m10r * a0r - m10i * a0i + m11r * a1r - m11i * a1i;
        colI[j][i1] = m10r * a0i + m10i * a0r + m11r * a1i + m11i * a1r;
      }
      __syncthreads();
    }
    for (int q = 0; q < 3; ++q) {
      if (t < 64) {
        const int jj = t >> 2, pp = t & 3;
        const int Bc = 3 - q, Bt = 2 - q;
        int fps[2], nf = 0;
        for (int b = 0; b < 4; ++b)
          if (b != Bc && b != Bt) fps[nf++] = b;
        const int i  = (1 << Bc) | ((pp & 1) << fps[0]) | (((pp >> 1) & 1) << fps[1]);
        const int i2 = i | (1 << Bt);
        float tr = colR[jj][i], ti = colI[jj][i];
        colR[jj][i] = colR[jj][i2]; colI[jj][i] = colI[jj][i2];
        colR[jj][i2] = tr;          colI[jj][i2] = ti;
      }
      __syncthreads();
    }
  }

  {
    const int jj = t >> 4, k = t & 15;
    float s0 = 0.f, s1 = 0.f, s2 = 0.f, s3 = 0.f;
#pragma unroll
    for (int i = 0; i < 16; ++i) {
      float pr = colR[jj][i] * colR[k][i] + colI[jj][i] * colI[k][i];
      s0 += ((i >> 3) & 1) ? -pr : pr;   // qubit 0 = bit 3
      s1 += ((i >> 2) & 1) ? -pr : pr;
      s2 += ((i >> 1) & 1) ? -pr : pr;
      s3 += ( i       & 1) ? -pr : pr;
    }
    S4[t] = make_float4(s0, s1, s2, s3);
  }
  __syncthreads();

  if (t < 81) {
    const int m[4] = { t / 27, (t / 9) % 3, (t / 3) % 3, t % 3 };
    float a0 = 0.f, a1 = 0.f, a2 = 0.f, a3 = 0.f;
    for (int c = 0; c < 16; ++c) {
      int jj = 0, kk = 0; bool ok = true;
      for (int q = 0; q < 4; ++q) {
        int jb, kb;
        if (m[q] == 1) { jb = (c >> q) & 1; kb = 1 - jb; }
        else { jb = kb = (m[q] >> 1); if ((c >> q) & 1) ok = false; }
        jj |= jb << (3 - q); kk |= kb << (3 - q);
      }
      if (!ok) continue;
      float4 sv = S4[jj * 16 + kk];
      a0 += sv.x; a1 += sv.y; a2 += sv.z; a3 += sv.w;
    }
    C[t * 4 + 0] = a0 * 0.0625f;
    C[t * 4 + 1] = a1 * 0.0625f;
    C[t * 4 + 2] = a2 * 0.0625f;
    C[t * 4 + 3] = a3 * 0.0625f;
  }
}

// ---------------------------------------------------------------------------
// Main kernel v3: 4 elements/thread, coefficients staged in LDS (bounds VGPR
// pressure -- no 81-wide global-load hoisting/spill), two-stage contraction
//   z_q = sum_a t01[a] * (sum_b C[a,b,q] * t23[b])      (360 FMA/element).
// ---------------------------------------------------------------------------
struct TF { float t01[9]; float t23[9]; };

__device__ __forceinline__ void build_t(const float4 a, TF& tf) {
  const float s0 = __sinf(a.x), c0 = __cosf(a.x);
  const float s1 = __sinf(a.y), c1 = __cosf(a.y);
  const float s2 = __sinf(a.z), c2 = __cosf(a.z);
  const float s3 = __sinf(a.w), c3 = __cosf(a.w);
  const float w0[3] = { 1.0f + c0, s0, 1.0f - c0 };
  const float w1[3] = { 1.0f + c1, s1, 1.0f - c1 };
  const float w2[3] = { 1.0f + c2, s2, 1.0f - c2 };
  const float w3[3] = { 1.0f + c3, s3, 1.0f - c3 };
#pragma unroll
  for (int i = 0; i < 3; ++i)
#pragma unroll
    for (int jj = 0; jj < 3; ++jj) {
      tf.t01[i * 3 + jj] = w0[i] * w1[jj];
      tf.t23[i * 3 + jj] = w2[i] * w3[jj];
    }
}

__global__ __launch_bounds__(256) void qmain(const float4* __restrict__ x4,
                                             const float4* __restrict__ C4,
                                             float4* __restrict__ out,
                                             int quarter) {
  __shared__ float4 Cs[81];
  const int t = threadIdx.x;
  if (t < 81) Cs[t] = C4[t];          // stage coefficients once per block

  const int gid = blockIdx.x * 256 + t;
  TF tf[4];
  build_t(x4[gid],               tf[0]);   // trig overlaps the LDS staging
  build_t(x4[gid + quarter],     tf[1]);
  build_t(x4[gid + 2 * quarter], tf[2]);
  build_t(x4[gid + 3 * quarter], tf[3]);
  __syncthreads();

  float2 z01[4], z23[4];
#pragma unroll
  for (int e = 0; e < 4; ++e) {
    z01[e] = make_float2(0.f, 0.f);
    z23[e] = make_float2(0.f, 0.f);
  }

#pragma unroll 1                       // pin live LDS-read window to one a-slice
  for (int a = 0; a < 9; ++a) {
    float2 v01[4], v23[4];
#pragma unroll
    for (int e = 0; e < 4; ++e) {
      v01[e] = make_float2(0.f, 0.f);
      v23[e] = make_float2(0.f, 0.f);
    }
#pragma unroll
    for (int b = 0; b < 9; ++b) {
      const float4 c = Cs[a * 9 + b];  // ds_read_b128, shared by 4 elements
#pragma unroll
      for (int e = 0; e < 4; ++e) {
        const float tb = tf[e].t23[b];
        v01[e].x = fmaf(c.x, tb, v01[e].x);
        v01[e].y = fmaf(c.y, tb, v01[e].y);
        v23[e].x = fmaf(c.z, tb, v23[e].x);
        v23[e].y = fmaf(c.w, tb, v23[e].y);
      }
    }
#pragma unroll
    for (int e = 0; e < 4; ++e) {
      const float ta = tf[e].t01[a];
      z01[e].x = fmaf(ta, v01[e].x, z01[e].x);
      z01[e].y = fmaf(ta, v01[e].y, z01[e].y);
      z23[e].x = fmaf(ta, v23[e].x, z23[e].x);
      z23[e].y = fmaf(ta, v23[e].y, z23[e].y);
    }
  }

  out[gid]               = make_float4(z01[0].x, z01[0].y, z23[0].x, z23[0].y);
  out[gid + quarter]     = make_float4(z01[1].x, z01[1].y, z23[1].x, z23[1].y);
  out[gid + 2 * quarter] = make_float4(z01[2].x, z01[2].y, z23[2].x, z23[2].y);
  out[gid + 3 * quarter] = make_float4(z01[3].x, z01[3].y, z23[3].x, z23[3].y);
}

extern "C" void kernel_launch(void* const* d_in, const int* in_sizes, int n_in,
                              void* d_out, int out_size, void* d_ws, size_t ws_size,
                              hipStream_t stream) {
  const float* x      = (const float*)d_in[0];
  const float* params = (const float*)d_in[1];
  float* C = (float*)d_ws;   // 324 floats

  qprecomp<<<1, 256, 0, stream>>>(params, C);

  const int M       = in_sizes[0] / 4;   // 1,048,576 patches
  const int quarter = M / 4;             // 262,144 threads, 4 elems each
  const int blocks  = quarter / 256;     // 1024
  qmain<<<blocks, 256, 0, stream>>>((const float4*)x, (const float4*)C,
                                    (float4*)d_out, quarter);
}